// Round 1
// baseline (47.145 us; speedup 1.0000x reference)
//
#include <hip/hip_runtime.h>
#include <hip/hip_bf16.h>

#define BATCH 8192
#define DDIM 512
#define FDIM 64
#define KD 64

typedef __attribute__((ext_vector_type(8))) short short8;
typedef __attribute__((ext_vector_type(4))) float f32x4;

static __device__ __forceinline__ unsigned short f2bf(float f) {
    __hip_bfloat16 h = __float2bfloat16(f);
    return *reinterpret_cast<unsigned short*>(&h);
}

// ---------------- x (f32) -> xb (bf16) ----------------
__global__ void cvt_kernel(const float* __restrict__ x, unsigned short* __restrict__ xb) {
    const int n4 = BATCH * DDIM / 4;
    for (int i = blockIdx.x * blockDim.x + threadIdx.x; i < n4; i += gridDim.x * blockDim.x) {
        float4 v = reinterpret_cast<const float4*>(x)[i];
        ushort4 o;
        o.x = f2bf(v.x); o.y = f2bf(v.y); o.z = f2bf(v.z); o.w = f2bf(v.w);
        reinterpret_cast<ushort4*>(xb)[i] = o;
    }
}

// ---------------- W^T (bf16, N-major): WT[j*D + i] = (i<j) ? dot(kernel[i,fd[j],:], kernel[j,fd[i],:]) : 0
__global__ void w_kernel(const float* __restrict__ kern, const int* __restrict__ fd,
                         unsigned short* __restrict__ WT) {
    const int j = blockIdx.y;
    const int i = blockIdx.x * 256 + threadIdx.x;
    float v = 0.f;
    if (i < j) {
        const float* a = kern + ((size_t)i * FDIM + fd[j]) * KD;
        const float* b = kern + ((size_t)j * FDIM + fd[i]) * KD;
#pragma unroll
        for (int k = 0; k < KD; k += 4) {
            float4 av = *reinterpret_cast<const float4*>(a + k);
            float4 bv = *reinterpret_cast<const float4*>(b + k);
            v += av.x * bv.x + av.y * bv.y + av.z * bv.z + av.w * bv.w;
        }
    }
    WT[(size_t)j * DDIM + i] = f2bf(v);
}

// ---------------- fused  out[b] += x[b,:] @ Wm @ x[b,:]  (MFMA bf16) ----------------
#define BM 64
#define BN 128
#define BK 32

__global__ __launch_bounds__(256) void quad_kernel(const unsigned short* __restrict__ xb,
                                                   const unsigned short* __restrict__ WT,
                                                   const float* __restrict__ x,
                                                   float* __restrict__ out) {
    __shared__ unsigned short As[BM * BK];   // [row][k], 16B-chunk XOR-swizzled
    __shared__ unsigned short Bs[BN * BK];   // [col][k], 16B-chunk XOR-swizzled

    const int tid = threadIdx.x;
    const int lane = tid & 63;
    const int w = tid >> 6;          // wave 0..3
    const int wm = w >> 1, wn = w & 1;
    const int ln = lane & 15, l4 = lane >> 4;
    const int mbase = blockIdx.x * BM;
    const int nbase = blockIdx.y * BN;

    f32x4 acc[2][4] = {};

    const int srow = tid >> 2;       // 0..63
    const int sc = tid & 3;          // 16B chunk 0..3

    for (int kk = 0; kk < DDIM; kk += BK) {
        // stage A tile (64 x 32 bf16)
        {
            int4 v = *reinterpret_cast<const int4*>(xb + (size_t)(mbase + srow) * DDIM + kk + sc * 8);
            int cs = sc ^ (srow & 3) ^ ((srow >> 2) & 3);
            *reinterpret_cast<int4*>(As + srow * BK + cs * 8) = v;
        }
        // stage B tile (128 x 32 bf16): two rows per thread
#pragma unroll
        for (int r = 0; r < 2; ++r) {
            int row = srow + r * 64;
            int4 v = *reinterpret_cast<const int4*>(WT + (size_t)(nbase + row) * DDIM + kk + sc * 8);
            int cs = sc ^ (row & 3) ^ ((row >> 2) & 3);
            *reinterpret_cast<int4*>(Bs + row * BK + cs * 8) = v;
        }
        __syncthreads();

        short8 a[2], b[4];
#pragma unroll
        for (int m = 0; m < 2; ++m) {
            int row = wm * 32 + m * 16 + ln;          // A row = lane&15
            int cs = l4 ^ (row & 3) ^ ((row >> 2) & 3);
            a[m] = *reinterpret_cast<const short8*>(As + row * BK + cs * 8);
        }
#pragma unroll
        for (int n = 0; n < 4; ++n) {
            int col = wn * 64 + n * 16 + ln;          // B col = lane&15
            int cs = l4 ^ (col & 3) ^ ((col >> 2) & 3);
            b[n] = *reinterpret_cast<const short8*>(Bs + col * BK + cs * 8);
        }
#pragma unroll
        for (int m = 0; m < 2; ++m)
#pragma unroll
            for (int n = 0; n < 4; ++n)
                acc[m][n] = __builtin_amdgcn_mfma_f32_16x16x32_bf16(a[m], b[n], acc[m][n], 0, 0, 0);
        __syncthreads();
    }

    // epilogue: out[row] += sum_col y[row][col] * x[row][col]
#pragma unroll
    for (int m = 0; m < 2; ++m) {
#pragma unroll
        for (int q = 0; q < 4; ++q) {
            int grow = mbase + wm * 32 + m * 16 + l4 * 4 + q;   // C/D: row=(lane>>4)*4+reg
            float s = 0.f;
#pragma unroll
            for (int n = 0; n < 4; ++n) {
                int gcol = nbase + wn * 64 + n * 16 + ln;        // C/D: col=lane&15
                s += acc[m][n][q] * x[(size_t)grow * DDIM + gcol];
            }
#pragma unroll
            for (int off = 1; off < 16; off <<= 1)
                s += __shfl_xor(s, off, 64);
            if (ln == 0) atomicAdd(out + grow, s);
        }
    }
}

extern "C" void kernel_launch(void* const* d_in, const int* in_sizes, int n_in,
                              void* d_out, int out_size, void* d_ws, size_t ws_size,
                              hipStream_t stream) {
    const float* x = (const float*)d_in[0];
    const float* kern = (const float*)d_in[1];
    const int* fd = (const int*)d_in[2];
    float* out = (float*)d_out;

    unsigned short* xb = (unsigned short*)d_ws;
    unsigned short* WT = xb + (size_t)BATCH * DDIM;

    hipMemsetAsync(out, 0, BATCH * sizeof(float), stream);
    cvt_kernel<<<2048, 256, 0, stream>>>(x, xb);
    dim3 wgrid(2, DDIM);
    w_kernel<<<wgrid, 256, 0, stream>>>(kern, fd, WT);
    dim3 qgrid(BATCH / BM, DDIM / BN);
    quad_kernel<<<qgrid, 256, 0, stream>>>(xb, WT, x, out);
}